// Round 7
// baseline (196.091 us; speedup 1.0000x reference)
//
#include <hip/hip_runtime.h>
#include <hip/hip_bf16.h>

#define NFEAT 256
#define NHID  128

typedef short s16x8 __attribute__((ext_vector_type(8)));
typedef float f32x4 __attribute__((ext_vector_type(4)));
typedef float f32x2 __attribute__((ext_vector_type(2)));

static __device__ __forceinline__ ushort bfbits(float f) {
  __hip_bfloat16 h = __float2bfloat16(f);
  return *reinterpret_cast<ushort*>(&h);
}

// ---------------------------------------------------------------------------
// W transpose+convert: Wt[n][k] = bf16(W[k][n])   (one-time, 32K elems)
// ---------------------------------------------------------------------------
__global__ __launch_bounds__(256) void wcvt_kernel(
    const float* __restrict__ W, ushort* __restrict__ Wt) {
  const int id = blockIdx.x * 256 + threadIdx.x;  // grid 128
  const int k = id >> 7, n = id & 127;            // coalesced read of W[k][n]
  Wt[n * NFEAT + k] = bfbits(W[id]);
}

// ---------------------------------------------------------------------------
// MFMA GEMM: support_bf16 = bf16(x @ W).  Block = 256 thr = 4 waves.
// Tile: BM=64 x NHID=128; K chunked by 64.  LDS XOR-swizzle (T2/G4).
// ---------------------------------------------------------------------------
__global__ __launch_bounds__(256) void gemm_mfma(
    const float* __restrict__ x, const ushort* __restrict__ Wt,
    ushort* __restrict__ sup, int n_nodes) {
  __shared__ ushort As[64 * 64];   // [r][k] swizzled, 8 KB
  __shared__ ushort Bs[128 * 64];  // [n][k] swizzled, 16 KB
  const int t = threadIdx.x;
  const int wid = t >> 6;
  const int lane = t & 63;
  const int rowBase = blockIdx.x * 64;

  f32x4 acc[4][2];
#pragma unroll
  for (int m = 0; m < 4; ++m)
#pragma unroll
    for (int n = 0; n < 2; ++n) acc[m][n] = (f32x4){0.f, 0.f, 0.f, 0.f};

  const float4* x4 = (const float4*)x;

  for (int kc = 0; kc < 4; ++kc) {
    __syncthreads();
#pragma unroll
    for (int it = 0; it < 4; ++it) {
      const int i4 = t + it * 256;
      const int r = i4 >> 4, k4 = i4 & 15;
      const int row = rowBase + r;
      float4 v = make_float4(0.f, 0.f, 0.f, 0.f);
      if (row < n_nodes) v = x4[(size_t)row * (NFEAT / 4) + kc * 16 + k4];
      ushort4 h;
      h.x = bfbits(v.x); h.y = bfbits(v.y); h.z = bfbits(v.z); h.w = bfbits(v.w);
      int byte = (r << 7) + (k4 << 3);
      byte ^= (r & 7) << 4;
      *(ushort4*)((char*)As + byte) = h;
    }
#pragma unroll
    for (int it = 0; it < 8; ++it) {
      const int idx = t + it * 256;
      const int col = idx >> 4, k4 = idx & 15;
      const ushort4 h = *(const ushort4*)(Wt + col * NFEAT + kc * 64 + k4 * 4);
      int byte = (col << 7) + (k4 << 3);
      byte ^= (col & 7) << 4;
      *(ushort4*)((char*)Bs + byte) = h;
    }
    __syncthreads();
#pragma unroll
    for (int ks = 0; ks < 2; ++ks) {
      const int k0 = ks * 32 + (lane >> 4) * 8;
      s16x8 af[4], bfr[2];
#pragma unroll
      for (int m = 0; m < 4; ++m) {
        const int r = m * 16 + (lane & 15);
        int byte = (r << 7) + (k0 << 1);
        byte ^= (r & 7) << 4;
        af[m] = *(const s16x8*)((const char*)As + byte);
      }
#pragma unroll
      for (int n = 0; n < 2; ++n) {
        const int c = wid * 32 + n * 16 + (lane & 15);
        int byte = (c << 7) + (k0 << 1);
        byte ^= (c & 7) << 4;
        bfr[n] = *(const s16x8*)((const char*)Bs + byte);
      }
#pragma unroll
      for (int m = 0; m < 4; ++m)
#pragma unroll
        for (int n = 0; n < 2; ++n)
          acc[m][n] = __builtin_amdgcn_mfma_f32_16x16x32_bf16(af[m], bfr[n], acc[m][n], 0, 0, 0);
    }
  }

  // C/D layout: col = lane&15, row = (lane>>4)*4 + reg   [m89-verified]
#pragma unroll
  for (int m = 0; m < 4; ++m) {
#pragma unroll
    for (int rr = 0; rr < 4; ++rr) {
      const int row = rowBase + m * 16 + (lane >> 4) * 4 + rr;
      if (row < n_nodes) {
#pragma unroll
        for (int n = 0; n < 2; ++n) {
          const int col = wid * 32 + n * 16 + (lane & 15);
          sup[(size_t)row * NHID + col] = bfbits(acc[m][n][rr]);
        }
      }
    }
  }
}

// ---------------------------------------------------------------------------
// CSR count+rank with line-padded counters: counts[dst << cshift].
// cshift=5 -> one counter per 128B line: same-line RMW chains drop from
// ~500 (packed) to ~avg-degree (16); lines resolve in parallel at LLC.
// ---------------------------------------------------------------------------
__global__ __launch_bounds__(256) void count_rank_kernel(
    const int* __restrict__ edst, int* __restrict__ counts,
    int* __restrict__ rank, int n_edges, int cshift) {
  const int e = blockIdx.x * 256 + threadIdx.x;
  if (e < n_edges) rank[e] = atomicAdd(&counts[(size_t)(uint)edst[e] << cshift], 1);
}

// ---------------------------------------------------------------------------
// Hierarchical exclusive scan over strided counts -> row_start
// ---------------------------------------------------------------------------
__global__ __launch_bounds__(256) void scan1_kernel(
    const int* __restrict__ in, int* __restrict__ exc,
    int* __restrict__ bsums, int n, int cshift) {
  const int tid = threadIdx.x;
  const int lane = tid & 63, wid = tid >> 6;
  const int base = blockIdx.x * 1024 + tid * 4;
  int v0 = 0, v1 = 0, v2 = 0, v3 = 0;
  if (base + 0 < n) v0 = in[(size_t)(base + 0) << cshift];
  if (base + 1 < n) v1 = in[(size_t)(base + 1) << cshift];
  if (base + 2 < n) v2 = in[(size_t)(base + 2) << cshift];
  if (base + 3 < n) v3 = in[(size_t)(base + 3) << cshift];
  const int tsum = v0 + v1 + v2 + v3;
  int t = tsum;
#pragma unroll
  for (int d = 1; d < 64; d <<= 1) {
    int u = __shfl_up(t, d);
    if (lane >= d) t += u;
  }
  __shared__ int wtot[4], wpre[4];
  if (lane == 63) wtot[wid] = t;
  __syncthreads();
  if (tid == 0) {
    int s = 0;
    for (int w = 0; w < 4; ++w) { wpre[w] = s; s += wtot[w]; }
    bsums[blockIdx.x] = s;
  }
  __syncthreads();
  const int off = (t - tsum) + wpre[wid];
  if (base + 0 < n) exc[base + 0] = off;
  if (base + 1 < n) exc[base + 1] = off + v0;
  if (base + 2 < n) exc[base + 2] = off + v0 + v1;
  if (base + 3 < n) exc[base + 3] = off + v0 + v1 + v2;
}

__global__ __launch_bounds__(256) void scan2_kernel(int* __restrict__ bsums, int nb) {
  const int tid = threadIdx.x;
  const int lane = tid & 63, wid = tid >> 6;
  const int v = (tid < nb) ? bsums[tid] : 0;
  int t = v;
#pragma unroll
  for (int d = 1; d < 64; d <<= 1) {
    int u = __shfl_up(t, d);
    if (lane >= d) t += u;
  }
  __shared__ int wtot[4], wpre[4];
  if (lane == 63) wtot[wid] = t;
  __syncthreads();
  if (tid == 0) {
    int s = 0;
    for (int w = 0; w < 4; ++w) { wpre[w] = s; s += wtot[w]; }
  }
  __syncthreads();
  const int exc = (t - v) + wpre[wid];
  if (tid < nb) bsums[tid] = exc;
}

__global__ __launch_bounds__(256) void scan3_kernel(
    const int* __restrict__ exc, const int* __restrict__ bsums,
    int* __restrict__ row_start, int n, int n_edges) {
  const int i = blockIdx.x * 256 + threadIdx.x;
  if (i < n) row_start[i] = exc[i] + bsums[i >> 10];
  if (i == 0) row_start[n] = n_edges;
}

__global__ __launch_bounds__(256) void fill_kernel(
    const int* __restrict__ esrc, const int* __restrict__ edst,
    const float* __restrict__ ew, const int* __restrict__ rank,
    const int* __restrict__ row_start, int2* __restrict__ packed, int n_edges) {
  const int e = blockIdx.x * 256 + threadIdx.x;
  if (e >= n_edges) return;
  const int pos = row_start[edst[e]] + rank[e];
  packed[pos] = make_int2(esrc[e], __float_as_int(ew[e]));
}

// ---------------------------------------------------------------------------
// Aggregation: 1 wave per node; lane owns 2 cols (uint = 2 bf16); SGPR-
// uniform packed loads; x4 unroll -> 4 independent gathers in flight.
// Fused bias + ReLU, NT float2 store.
// ---------------------------------------------------------------------------
__global__ __launch_bounds__(256) void agg_kernel(
    const ushort* __restrict__ sup, const int2* __restrict__ packed,
    const int* __restrict__ row_start, const float* __restrict__ bias,
    float* __restrict__ out, int n_nodes) {
  const int node = blockIdx.x * 4 + (threadIdx.x >> 6);
  if (node >= n_nodes) return;
  const int lane = threadIdx.x & 63;
  const int start = __builtin_amdgcn_readfirstlane(row_start[node]);
  const int end   = __builtin_amdgcn_readfirstlane(row_start[node + 1]);

  float a0 = 0.f, a1 = 0.f, b0 = 0.f, b1 = 0.f;
  int i = start;
  for (; i + 3 < end; i += 4) {
    const int2 e0 = packed[i + 0];
    const int2 e1 = packed[i + 1];
    const int2 e2 = packed[i + 2];
    const int2 e3 = packed[i + 3];
    const uint u0 = *(const uint*)(sup + ((size_t)(uint)e0.x << 7) + lane * 2);
    const uint u1 = *(const uint*)(sup + ((size_t)(uint)e1.x << 7) + lane * 2);
    const uint u2 = *(const uint*)(sup + ((size_t)(uint)e2.x << 7) + lane * 2);
    const uint u3 = *(const uint*)(sup + ((size_t)(uint)e3.x << 7) + lane * 2);
    const float w0 = __int_as_float(e0.y);
    const float w1 = __int_as_float(e1.y);
    const float w2 = __int_as_float(e2.y);
    const float w3 = __int_as_float(e3.y);
    a0 += __uint_as_float(u0 << 16) * w0 + __uint_as_float(u2 << 16) * w2;
    a1 += __uint_as_float(u0 & 0xffff0000u) * w0 + __uint_as_float(u2 & 0xffff0000u) * w2;
    b0 += __uint_as_float(u1 << 16) * w1 + __uint_as_float(u3 << 16) * w3;
    b1 += __uint_as_float(u1 & 0xffff0000u) * w1 + __uint_as_float(u3 & 0xffff0000u) * w3;
  }
  for (; i < end; ++i) {
    const int2 e0 = packed[i];
    const uint u0 = *(const uint*)(sup + ((size_t)(uint)e0.x << 7) + lane * 2);
    const float w0 = __int_as_float(e0.y);
    a0 += __uint_as_float(u0 << 16) * w0;
    a1 += __uint_as_float(u0 & 0xffff0000u) * w0;
  }

  const float2 bb = ((const float2*)bias)[lane];
  f32x2 r;
  r.x = fmaxf(a0 + b0 + bb.x, 0.f);
  r.y = fmaxf(a1 + b1 + bb.y, 0.f);
  __builtin_nontemporal_store(r, (f32x2*)out + (size_t)node * (NHID / 2) + lane);
}

// ---------------------------------------------------------------------------
// Fallback (ws too small): atomic scatter over bf16 support
// ---------------------------------------------------------------------------
__global__ __launch_bounds__(256) void scatter_bf16_kernel(
    const ushort* __restrict__ sup, const int* __restrict__ esrc,
    const int* __restrict__ edst, const float* __restrict__ ew,
    float* __restrict__ out, int n_edges) {
  const long long idx = (long long)blockIdx.x * 256 + threadIdx.x;
  const int e = (int)(idx >> 6);
  const int c2 = (int)(idx & 63);
  if (e >= n_edges) return;
  const int s = esrc[e];
  const int d = edst[e];
  const float wt = ew[e];
  const uint u = *(const uint*)(sup + (size_t)s * NHID + c2 * 2);
  float* drow = out + (size_t)d * NHID + c2 * 2;
  atomicAdd(drow + 0, __uint_as_float(u << 16) * wt);
  atomicAdd(drow + 1, __uint_as_float(u & 0xffff0000u) * wt);
}

__global__ __launch_bounds__(256) void bias_relu_kernel(
    float* __restrict__ out, const float* __restrict__ b, int n4) {
  const int i = blockIdx.x * 256 + threadIdx.x;
  if (i >= n4) return;
  float4 v = ((float4*)out)[i];
  const float4 bb = ((const float4*)b)[i & (NHID / 4 - 1)];
  v.x = fmaxf(v.x + bb.x, 0.f);
  v.y = fmaxf(v.y + bb.y, 0.f);
  v.z = fmaxf(v.z + bb.z, 0.f);
  v.w = fmaxf(v.w + bb.w, 0.f);
  ((float4*)out)[i] = v;
}

static inline size_t align_up(size_t v, size_t a) { return (v + a - 1) & ~(a - 1); }

extern "C" void kernel_launch(void* const* d_in, const int* in_sizes, int n_in,
                              void* d_out, int out_size, void* d_ws, size_t ws_size,
                              hipStream_t stream) {
  const float* x    = (const float*)d_in[0];
  const int*   esrc = (const int*)d_in[1];
  const int*   edst = (const int*)d_in[2];
  const float* ew   = (const float*)d_in[3];
  const float* W    = (const float*)d_in[4];
  const float* b    = (const float*)d_in[5];
  float* out = (float*)d_out;

  const int n_nodes = in_sizes[0] / NFEAT;
  const int n_edges = in_sizes[1];

  // workspace layout; try line-padded counters (cshift=5) first, else packed
  for (int cshift = 5; cshift >= 0; cshift -= 5) {
    char* ws = (char*)d_ws;
    size_t off = 0;
    ushort* sup     = (ushort*)(ws + off); off = align_up(off + (size_t)n_nodes * NHID * 2, 256);
    ushort* Wt      = (ushort*)(ws + off); off = align_up(off + (size_t)NFEAT * NHID * 2, 256);
    int* counts     = (int*)(ws + off);    off = align_up(off + ((size_t)n_nodes << cshift) * 4, 256);
    int* exc        = (int*)(ws + off);    off = align_up(off + (size_t)n_nodes * 4, 256);
    int* bsums      = (int*)(ws + off);    off = align_up(off + 1024 * 4, 256);
    int* row_start  = (int*)(ws + off);    off = align_up(off + ((size_t)n_nodes + 1) * 4, 256);
    int* rank       = (int*)(ws + off);    off = align_up(off + (size_t)n_edges * 4, 256);
    int2* packed    = (int2*)(ws + off);   off = align_up(off + (size_t)n_edges * 8, 256);
    const bool csr_ok = (off <= ws_size) && (n_nodes <= 256 * 1024);

    if (csr_ok) {
      // 1) Wt = bf16(W^T); support = bf16(x @ W) via MFMA
      wcvt_kernel<<<(NFEAT * NHID) / 256, 256, 0, stream>>>(W, Wt);
      gemm_mfma<<<(n_nodes + 63) / 64, 256, 0, stream>>>(x, Wt, sup, n_nodes);

      // 2) CSR build (line-padded counters kill same-line RMW chains)
      hipMemsetAsync(counts, 0, ((size_t)n_nodes << cshift) * 4, stream);
      count_rank_kernel<<<(n_edges + 255) / 256, 256, 0, stream>>>(edst, counts, rank, n_edges, cshift);
      const int nb = (n_nodes + 1023) / 1024;
      scan1_kernel<<<nb, 256, 0, stream>>>(counts, exc, bsums, n_nodes, cshift);
      scan2_kernel<<<1, 256, 0, stream>>>(bsums, nb);
      scan3_kernel<<<(n_nodes + 255) / 256, 256, 0, stream>>>(exc, bsums, row_start, n_nodes, n_edges);
      fill_kernel<<<(n_edges + 255) / 256, 256, 0, stream>>>(esrc, edst, ew, rank, row_start, packed, n_edges);

      // 3) gather-sum + bias + relu
      agg_kernel<<<(n_nodes + 3) / 4, 256, 0, stream>>>(sup, packed, row_start, b, out, n_nodes);
      return;
    }
  }

  // fallback: minimal-ws path (sup + Wt only)
  {
    char* ws = (char*)d_ws;
    size_t off = 0;
    ushort* sup = (ushort*)(ws + off); off = align_up(off + (size_t)n_nodes * NHID * 2, 256);
    ushort* Wt  = (ushort*)(ws + off);
    wcvt_kernel<<<(NFEAT * NHID) / 256, 256, 0, stream>>>(W, Wt);
    gemm_mfma<<<(n_nodes + 63) / 64, 256, 0, stream>>>(x, Wt, sup, n_nodes);
    hipMemsetAsync(out, 0, (size_t)n_nodes * NHID * sizeof(float), stream);
    const long long threads = (long long)n_edges * 64;
    scatter_bf16_kernel<<<(int)((threads + 255) / 256), 256, 0, stream>>>(sup, esrc, edst, ew, out, n_edges);
    const int n4 = n_nodes * NHID / 4;
    bias_relu_kernel<<<(n4 + 255) / 256, 256, 0, stream>>>(out, b, n4);
  }
}

// Round 8
// 174.738 us; speedup vs baseline: 1.1222x; 1.1222x over previous
//
#include <hip/hip_runtime.h>
#include <hip/hip_bf16.h>

#define NFEAT 256
#define NHID  128
#define CSHIFT 5  // counts padded: one counter per 128B line

typedef short s16x8 __attribute__((ext_vector_type(8)));
typedef float f32x4 __attribute__((ext_vector_type(4)));
typedef float f32x2 __attribute__((ext_vector_type(2)));

static __device__ __forceinline__ ushort bfbits(float f) {
  __hip_bfloat16 h = __float2bfloat16(f);
  return *reinterpret_cast<ushort*>(&h);
}

// ---------------------------------------------------------------------------
// W transpose+convert: Wt[n][k] = bf16(W[k][n])   (one-time, 32K elems)
// ---------------------------------------------------------------------------
__global__ __launch_bounds__(256) void wcvt_kernel(
    const float* __restrict__ W, ushort* __restrict__ Wt) {
  const int id = blockIdx.x * 256 + threadIdx.x;  // grid 128
  const int k = id >> 7, n = id & 127;            // coalesced read of W[k][n]
  Wt[n * NFEAT + k] = bfbits(W[id]);
}

// ---------------------------------------------------------------------------
// Fused GEMM || CSR-count, interleaved 1:1 by blockIdx so both roles are
// co-resident on every CU: count waves occupy the VMEM/atomic queue (0.5%
// VALU) while gemm waves use MFMA+LDS.  Count role: 4 edges/thread, int4
// edst load, 4 independent with-return atomics in flight (4x MLP).
// Gemm role: support_bf16 = bf16(x @ W), BM=64 x NHID=128, K chunks of 64,
// LDS XOR-swizzled (T2/G4).
// ---------------------------------------------------------------------------
__global__ __launch_bounds__(256) void gemm_count_fused(
    const float* __restrict__ x, const ushort* __restrict__ Wt,
    ushort* __restrict__ sup, int n_nodes,
    const int* __restrict__ edst, int* __restrict__ counts,
    int* __restrict__ rank, int n_edges, int n_gemm, int n_count) {
  __shared__ ushort As[64 * 64];   // [r][k] swizzled, 8 KB
  __shared__ ushort Bs[128 * 64];  // [n][k] swizzled, 16 KB

  // role mapping: interleave count (role 0) / gemm (role 1) 1:1, leftovers
  // from the larger set at the end.
  const int idx = blockIdx.x;
  const int minv = (n_gemm < n_count) ? n_gemm : n_count;
  int role, sub;
  if (idx < 2 * minv) {
    role = idx & 1;
    sub = idx >> 1;
  } else {
    role = (n_gemm > n_count) ? 1 : 0;
    sub = minv + (idx - 2 * minv);
  }

  if (role == 0) {
    // ---- CSR count + rank: 4 edges per thread ----
    const int e0 = sub * 1024 + threadIdx.x * 4;
    if (e0 + 3 < n_edges) {
      const int4 d = *(const int4*)(edst + e0);
      int r0 = atomicAdd(&counts[(size_t)(uint)d.x << CSHIFT], 1);
      int r1 = atomicAdd(&counts[(size_t)(uint)d.y << CSHIFT], 1);
      int r2 = atomicAdd(&counts[(size_t)(uint)d.z << CSHIFT], 1);
      int r3 = atomicAdd(&counts[(size_t)(uint)d.w << CSHIFT], 1);
      *(int4*)(rank + e0) = make_int4(r0, r1, r2, r3);
    } else {
      for (int e = e0; e < n_edges && e < e0 + 4; ++e)
        rank[e] = atomicAdd(&counts[(size_t)(uint)edst[e] << CSHIFT], 1);
    }
    return;
  }

  // ---- MFMA GEMM ----
  const int t = threadIdx.x;
  const int wid = t >> 6;
  const int lane = t & 63;
  const int rowBase = sub * 64;
  if (rowBase >= n_nodes) return;

  f32x4 acc[4][2];
#pragma unroll
  for (int m = 0; m < 4; ++m)
#pragma unroll
    for (int n = 0; n < 2; ++n) acc[m][n] = (f32x4){0.f, 0.f, 0.f, 0.f};

  const float4* x4 = (const float4*)x;

  for (int kc = 0; kc < 4; ++kc) {
    __syncthreads();
#pragma unroll
    for (int it = 0; it < 4; ++it) {
      const int i4 = t + it * 256;
      const int r = i4 >> 4, k4 = i4 & 15;
      const int row = rowBase + r;
      float4 v = make_float4(0.f, 0.f, 0.f, 0.f);
      if (row < n_nodes) v = x4[(size_t)row * (NFEAT / 4) + kc * 16 + k4];
      ushort4 h;
      h.x = bfbits(v.x); h.y = bfbits(v.y); h.z = bfbits(v.z); h.w = bfbits(v.w);
      int byte = (r << 7) + (k4 << 3);
      byte ^= (r & 7) << 4;
      *(ushort4*)((char*)As + byte) = h;
    }
#pragma unroll
    for (int it = 0; it < 8; ++it) {
      const int i2 = t + it * 256;
      const int col = i2 >> 4, k4 = i2 & 15;
      const ushort4 h = *(const ushort4*)(Wt + col * NFEAT + kc * 64 + k4 * 4);
      int byte = (col << 7) + (k4 << 3);
      byte ^= (col & 7) << 4;
      *(ushort4*)((char*)Bs + byte) = h;
    }
    __syncthreads();
#pragma unroll
    for (int ks = 0; ks < 2; ++ks) {
      const int k0 = ks * 32 + (lane >> 4) * 8;
      s16x8 af[4], bfr[2];
#pragma unroll
      for (int m = 0; m < 4; ++m) {
        const int r = m * 16 + (lane & 15);
        int byte = (r << 7) + (k0 << 1);
        byte ^= (r & 7) << 4;
        af[m] = *(const s16x8*)((const char*)As + byte);
      }
#pragma unroll
      for (int n = 0; n < 2; ++n) {
        const int c = wid * 32 + n * 16 + (lane & 15);
        int byte = (c << 7) + (k0 << 1);
        byte ^= (c & 7) << 4;
        bfr[n] = *(const s16x8*)((const char*)Bs + byte);
      }
#pragma unroll
      for (int m = 0; m < 4; ++m)
#pragma unroll
        for (int n = 0; n < 2; ++n)
          acc[m][n] = __builtin_amdgcn_mfma_f32_16x16x32_bf16(af[m], bfr[n], acc[m][n], 0, 0, 0);
    }
  }

  // C/D layout: col = lane&15, row = (lane>>4)*4 + reg   [m89-verified]
#pragma unroll
  for (int m = 0; m < 4; ++m) {
#pragma unroll
    for (int rr = 0; rr < 4; ++rr) {
      const int row = rowBase + m * 16 + (lane >> 4) * 4 + rr;
      if (row < n_nodes) {
#pragma unroll
        for (int n = 0; n < 2; ++n) {
          const int col = wid * 32 + n * 16 + (lane & 15);
          sup[(size_t)row * NHID + col] = bfbits(acc[m][n][rr]);
        }
      }
    }
  }
}

// ---------------------------------------------------------------------------
// Hierarchical exclusive scan over strided counts -> row_start
// ---------------------------------------------------------------------------
__global__ __launch_bounds__(256) void scan1_kernel(
    const int* __restrict__ in, int* __restrict__ exc,
    int* __restrict__ bsums, int n) {
  const int tid = threadIdx.x;
  const int lane = tid & 63, wid = tid >> 6;
  const int base = blockIdx.x * 1024 + tid * 4;
  int v0 = 0, v1 = 0, v2 = 0, v3 = 0;
  if (base + 0 < n) v0 = in[(size_t)(base + 0) << CSHIFT];
  if (base + 1 < n) v1 = in[(size_t)(base + 1) << CSHIFT];
  if (base + 2 < n) v2 = in[(size_t)(base + 2) << CSHIFT];
  if (base + 3 < n) v3 = in[(size_t)(base + 3) << CSHIFT];
  const int tsum = v0 + v1 + v2 + v3;
  int t = tsum;
#pragma unroll
  for (int d = 1; d < 64; d <<= 1) {
    int u = __shfl_up(t, d);
    if (lane >= d) t += u;
  }
  __shared__ int wtot[4], wpre[4];
  if (lane == 63) wtot[wid] = t;
  __syncthreads();
  if (tid == 0) {
    int s = 0;
    for (int w = 0; w < 4; ++w) { wpre[w] = s; s += wtot[w]; }
    bsums[blockIdx.x] = s;
  }
  __syncthreads();
  const int off = (t - tsum) + wpre[wid];
  if (base + 0 < n) exc[base + 0] = off;
  if (base + 1 < n) exc[base + 1] = off + v0;
  if (base + 2 < n) exc[base + 2] = off + v0 + v1;
  if (base + 3 < n) exc[base + 3] = off + v0 + v1 + v2;
}

__global__ __launch_bounds__(256) void scan2_kernel(int* __restrict__ bsums, int nb) {
  const int tid = threadIdx.x;
  const int lane = tid & 63, wid = tid >> 6;
  const int v = (tid < nb) ? bsums[tid] : 0;
  int t = v;
#pragma unroll
  for (int d = 1; d < 64; d <<= 1) {
    int u = __shfl_up(t, d);
    if (lane >= d) t += u;
  }
  __shared__ int wtot[4], wpre[4];
  if (lane == 63) wtot[wid] = t;
  __syncthreads();
  if (tid == 0) {
    int s = 0;
    for (int w = 0; w < 4; ++w) { wpre[w] = s; s += wtot[w]; }
  }
  __syncthreads();
  const int exc = (t - v) + wpre[wid];
  if (tid < nb) bsums[tid] = exc;
}

__global__ __launch_bounds__(256) void scan3_kernel(
    const int* __restrict__ exc, const int* __restrict__ bsums,
    int* __restrict__ row_start, int n, int n_edges) {
  const int i = blockIdx.x * 256 + threadIdx.x;
  if (i < n) row_start[i] = exc[i] + bsums[i >> 10];
  if (i == 0) row_start[n] = n_edges;
}

__global__ __launch_bounds__(256) void fill_kernel(
    const int* __restrict__ esrc, const int* __restrict__ edst,
    const float* __restrict__ ew, const int* __restrict__ rank,
    const int* __restrict__ row_start, int2* __restrict__ packed, int n_edges) {
  const int e = blockIdx.x * 256 + threadIdx.x;
  if (e >= n_edges) return;
  const int pos = row_start[edst[e]] + rank[e];
  packed[pos] = make_int2(esrc[e], __float_as_int(ew[e]));
}

// ---------------------------------------------------------------------------
// Aggregation: 1 wave per node; lane owns 2 cols (uint = 2 bf16); SGPR-
// uniform packed loads; x4 unroll -> 4 independent gathers in flight.
// Fused bias + ReLU, NT float2 store.
// ---------------------------------------------------------------------------
__global__ __launch_bounds__(256) void agg_kernel(
    const ushort* __restrict__ sup, const int2* __restrict__ packed,
    const int* __restrict__ row_start, const float* __restrict__ bias,
    float* __restrict__ out, int n_nodes) {
  const int node = blockIdx.x * 4 + (threadIdx.x >> 6);
  if (node >= n_nodes) return;
  const int lane = threadIdx.x & 63;
  const int start = __builtin_amdgcn_readfirstlane(row_start[node]);
  const int end   = __builtin_amdgcn_readfirstlane(row_start[node + 1]);

  float a0 = 0.f, a1 = 0.f, b0 = 0.f, b1 = 0.f;
  int i = start;
  for (; i + 3 < end; i += 4) {
    const int2 e0 = packed[i + 0];
    const int2 e1 = packed[i + 1];
    const int2 e2 = packed[i + 2];
    const int2 e3 = packed[i + 3];
    const uint u0 = *(const uint*)(sup + ((size_t)(uint)e0.x << 7) + lane * 2);
    const uint u1 = *(const uint*)(sup + ((size_t)(uint)e1.x << 7) + lane * 2);
    const uint u2 = *(const uint*)(sup + ((size_t)(uint)e2.x << 7) + lane * 2);
    const uint u3 = *(const uint*)(sup + ((size_t)(uint)e3.x << 7) + lane * 2);
    const float w0 = __int_as_float(e0.y);
    const float w1 = __int_as_float(e1.y);
    const float w2 = __int_as_float(e2.y);
    const float w3 = __int_as_float(e3.y);
    a0 += __uint_as_float(u0 << 16) * w0 + __uint_as_float(u2 << 16) * w2;
    a1 += __uint_as_float(u0 & 0xffff0000u) * w0 + __uint_as_float(u2 & 0xffff0000u) * w2;
    b0 += __uint_as_float(u1 << 16) * w1 + __uint_as_float(u3 << 16) * w3;
    b1 += __uint_as_float(u1 & 0xffff0000u) * w1 + __uint_as_float(u3 & 0xffff0000u) * w3;
  }
  for (; i < end; ++i) {
    const int2 e0 = packed[i];
    const uint u0 = *(const uint*)(sup + ((size_t)(uint)e0.x << 7) + lane * 2);
    const float w0 = __int_as_float(e0.y);
    a0 += __uint_as_float(u0 << 16) * w0;
    a1 += __uint_as_float(u0 & 0xffff0000u) * w0;
  }

  const float2 bb = ((const float2*)bias)[lane];
  f32x2 r;
  r.x = fmaxf(a0 + b0 + bb.x, 0.f);
  r.y = fmaxf(a1 + b1 + bb.y, 0.f);
  __builtin_nontemporal_store(r, (f32x2*)out + (size_t)node * (NHID / 2) + lane);
}

// ---------------------------------------------------------------------------
// Fallback (ws too small): atomic scatter over bf16 support
// ---------------------------------------------------------------------------
__global__ __launch_bounds__(256) void scatter_bf16_kernel(
    const ushort* __restrict__ sup, const int* __restrict__ esrc,
    const int* __restrict__ edst, const float* __restrict__ ew,
    float* __restrict__ out, int n_edges) {
  const long long idx = (long long)blockIdx.x * 256 + threadIdx.x;
  const int e = (int)(idx >> 6);
  const int c2 = (int)(idx & 63);
  if (e >= n_edges) return;
  const int s = esrc[e];
  const int d = edst[e];
  const float wt = ew[e];
  const uint u = *(const uint*)(sup + (size_t)s * NHID + c2 * 2);
  float* drow = out + (size_t)d * NHID + c2 * 2;
  atomicAdd(drow + 0, __uint_as_float(u << 16) * wt);
  atomicAdd(drow + 1, __uint_as_float(u & 0xffff0000u) * wt);
}

__global__ __launch_bounds__(256) void bias_relu_kernel(
    float* __restrict__ out, const float* __restrict__ b, int n4) {
  const int i = blockIdx.x * 256 + threadIdx.x;
  if (i >= n4) return;
  float4 v = ((float4*)out)[i];
  const float4 bb = ((const float4*)b)[i & (NHID / 4 - 1)];
  v.x = fmaxf(v.x + bb.x, 0.f);
  v.y = fmaxf(v.y + bb.y, 0.f);
  v.z = fmaxf(v.z + bb.z, 0.f);
  v.w = fmaxf(v.w + bb.w, 0.f);
  ((float4*)out)[i] = v;
}

static inline size_t align_up(size_t v, size_t a) { return (v + a - 1) & ~(a - 1); }

extern "C" void kernel_launch(void* const* d_in, const int* in_sizes, int n_in,
                              void* d_out, int out_size, void* d_ws, size_t ws_size,
                              hipStream_t stream) {
  const float* x    = (const float*)d_in[0];
  const int*   esrc = (const int*)d_in[1];
  const int*   edst = (const int*)d_in[2];
  const float* ew   = (const float*)d_in[3];
  const float* W    = (const float*)d_in[4];
  const float* b    = (const float*)d_in[5];
  float* out = (float*)d_out;

  const int n_nodes = in_sizes[0] / NFEAT;
  const int n_edges = in_sizes[1];

  // workspace layout (~60 MB at N=100k, E=1.6M with padded counters)
  char* ws = (char*)d_ws;
  size_t off = 0;
  ushort* sup     = (ushort*)(ws + off); off = align_up(off + (size_t)n_nodes * NHID * 2, 256);
  ushort* Wt      = (ushort*)(ws + off); off = align_up(off + (size_t)NFEAT * NHID * 2, 256);
  int* counts     = (int*)(ws + off);    off = align_up(off + ((size_t)n_nodes << CSHIFT) * 4, 256);
  int* exc        = (int*)(ws + off);    off = align_up(off + (size_t)n_nodes * 4, 256);
  int* bsums      = (int*)(ws + off);    off = align_up(off + 1024 * 4, 256);
  int* row_start  = (int*)(ws + off);    off = align_up(off + ((size_t)n_nodes + 1) * 4, 256);
  int* rank       = (int*)(ws + off);    off = align_up(off + align_up((size_t)n_edges, 4) * 4, 256);
  int2* packed    = (int2*)(ws + off);   off = align_up(off + (size_t)n_edges * 8, 256);
  const bool csr_ok = (off <= ws_size) && (n_nodes <= 256 * 1024);

  const int n_gemm = (n_nodes + 63) / 64;

  if (csr_ok) {
    // 1) Wt = bf16(W^T); zero padded counters
    wcvt_kernel<<<(NFEAT * NHID) / 256, 256, 0, stream>>>(W, Wt);
    hipMemsetAsync(counts, 0, ((size_t)n_nodes << CSHIFT) * 4, stream);

    // 2) fused GEMM || count+rank, 1:1 interleaved for co-residency
    const int n_count = (n_edges + 1023) / 1024;
    gemm_count_fused<<<n_gemm + n_count, 256, 0, stream>>>(
        x, Wt, sup, n_nodes, edst, counts, rank, n_edges, n_gemm, n_count);

    // 3) scan + fill
    const int nb = (n_nodes + 1023) / 1024;
    scan1_kernel<<<nb, 256, 0, stream>>>(counts, exc, bsums, n_nodes);
    scan2_kernel<<<1, 256, 0, stream>>>(bsums, nb);
    scan3_kernel<<<(n_nodes + 255) / 256, 256, 0, stream>>>(exc, bsums, row_start, n_nodes, n_edges);
    fill_kernel<<<(n_edges + 255) / 256, 256, 0, stream>>>(esrc, edst, ew, rank, row_start, packed, n_edges);

    // 4) gather-sum + bias + relu
    agg_kernel<<<(n_nodes + 3) / 4, 256, 0, stream>>>(sup, packed, row_start, b, out, n_nodes);
  } else {
    // fallback: minimal-ws path (sup + Wt only), gemm role only
    wcvt_kernel<<<(NFEAT * NHID) / 256, 256, 0, stream>>>(W, Wt);
    gemm_count_fused<<<n_gemm, 256, 0, stream>>>(
        x, Wt, sup, n_nodes, edst, (int*)d_ws, (int*)d_ws, 0, n_gemm, 0);
    hipMemsetAsync(out, 0, (size_t)n_nodes * NHID * sizeof(float), stream);
    const long long threads = (long long)n_edges * 64;
    scatter_bf16_kernel<<<(int)((threads + 255) / 256), 256, 0, stream>>>(sup, esrc, edst, ew, out, n_edges);
    const int n4 = n_nodes * NHID / 4;
    bias_relu_kernel<<<(n4 + 255) / 256, 256, 0, stream>>>(out, b, n4);
  }
}